// Round 3
// baseline (503.838 us; speedup 1.0000x reference)
//
#include <hip/hip_runtime.h>
#include <hip/hip_bf16.h>
#include <stdint.h>

// GAT layer: B=8, N=2048, F_IN=F_OUT=128
// h = x @ W^T ; s1 = h@a1 ; s2 = h@a2
// e[i,j] = leaky_relu(s1[i]+s2[j], 0.2); masked softmax over j (adj>0); out = attn @ h
// Scores are rank-1 => no NxN score GEMM. Scores are O(0.05) => exp() without
// max-subtraction is safe; masked entries contribute exactly 0 => softmax
// ratio identical to reference.
//
// Dtype contract (established R1/R2): ALL per reference — input/W/a fp32,
// adj int32, OUTPUT fp32. (R1 NaN proved inputs fp32; R2's decorrelated
// error proved output buffer is read as fp32, not bf16.)

#define B_ 8
#define N_ 2048
#define FD 128
#define ALPHA_ 0.2f

#define TI 16   // rows per block in attention kernel
#define TJ 64   // j-tile

__device__ __forceinline__ float bf2f(unsigned short u) {
    union { uint32_t i; float f; } v;
    v.i = ((uint32_t)u) << 16;
    return v.f;
}
__device__ __forceinline__ unsigned short f2bf(float f) {
    union { float f; uint32_t i; } v;
    v.f = f;
    uint32_t x = v.i;
    uint32_t r = (x + 0x7fffu + ((x >> 16) & 1u)) >> 16;  // RNE
    return (unsigned short)r;
}

// ---------------------------------------------------------------------------
// Kernel 1: h[row][o] = sum_f x[row][f]*W[o][f]; s1=h@a1, s2=h@a2
// grid = B*N blocks, 128 threads (one per output channel o)
// ---------------------------------------------------------------------------
__global__ __launch_bounds__(128) void gat_h_kernel(
    const float* __restrict__ x,        // (B*N, 128) fp32
    const float* __restrict__ W,        // (128, 128) fp32, row o contiguous
    const float* __restrict__ a,        // (256,) fp32
    unsigned short* __restrict__ h_bf,  // out: (B*N, 128) bf16
    float* __restrict__ s1,             // out: (B*N,)
    float* __restrict__ s2)             // out: (B*N,)
{
    const int row = blockIdx.x;
    const int o = threadIdx.x;

    __shared__ float xs[FD];
    xs[o] = x[(size_t)row * FD + o];
    __syncthreads();

    const float* wr = W + (size_t)o * FD;
    float acc = 0.f;
#pragma unroll
    for (int f = 0; f < FD; f += 4) {
        float4 wv = *(const float4*)(wr + f);
        acc += wv.x * xs[f + 0] + wv.y * xs[f + 1];
        acc += wv.z * xs[f + 2] + wv.w * xs[f + 3];
    }
    h_bf[(size_t)row * FD + o] = f2bf(acc);

    __shared__ float r1[FD];
    __shared__ float r2[FD];
    r1[o] = acc * a[o];
    r2[o] = acc * a[FD + o];
    __syncthreads();
#pragma unroll
    for (int s = 64; s > 0; s >>= 1) {
        if (o < s) { r1[o] += r1[o + s]; r2[o] += r2[o + s]; }
        __syncthreads();
    }
    if (o == 0) { s1[row] = r1[0]; s2[row] = r2[0]; }
}

// ---------------------------------------------------------------------------
// Kernel 2: fused masked-softmax + PV.  One block = (batch b, 16 rows i).
// 128 threads; thread t owns output channel o=t for all 16 rows (acc[16]).
// Per 64-wide j-tile: phase 1 computes P (16x64) into LDS (stored transposed
// P[j][i] so phase 2 reads are float4 broadcasts); phase 2 accumulates
// acc[i] += P[i][j] * h[j][o].  Row-sums accumulated alongside; divide once.
// ---------------------------------------------------------------------------
__global__ __launch_bounds__(128) void gat_attn_kernel(
    const int* __restrict__ adj,            // (B, N, N) int32
    const unsigned short* __restrict__ h_bf,// (B*N, 128) bf16
    const float* __restrict__ s1,
    const float* __restrict__ s2,
    float* __restrict__ out)                // (B*N, 128) fp32
{
    const int b = blockIdx.y;
    const int i0 = blockIdx.x * TI;
    const int t = threadIdx.x;
    const int o = t;

    __shared__ float P[TJ][TI];     // transposed: P[j_local][i_local]
    __shared__ float rs_part[128];
    __shared__ float rs[TI];

    float acc[TI];
#pragma unroll
    for (int i = 0; i < TI; i++) acc[i] = 0.f;
    float rs_loc = 0.f;

    // phase-1 mapping: thread t computes row my_i, 8 consecutive j at jo
    const int my_i = t >> 3;
    const int jo = (t & 7) * 8;
    const float s1v = s1[b * N_ + i0 + my_i];
    const int* adjrow = adj + ((size_t)b * N_ + (i0 + my_i)) * N_ + jo;
    const float* s2row = s2 + b * N_ + jo;
    const unsigned short* hb = h_bf + (size_t)b * N_ * FD + o;

    for (int jt = 0; jt < N_; jt += TJ) {
        // ---- phase 1: build P tile ----
        int4 av0 = *(const int4*)(adjrow + jt);
        int4 av1 = *(const int4*)(adjrow + jt + 4);
        float4 sv0 = *(const float4*)(s2row + jt);
        float4 sv1 = *(const float4*)(s2row + jt + 4);
        int am[8] = { av0.x, av0.y, av0.z, av0.w, av1.x, av1.y, av1.z, av1.w };
        float sv[8] = { sv0.x, sv0.y, sv0.z, sv0.w, sv1.x, sv1.y, sv1.z, sv1.w };
        float p[8];
#pragma unroll
        for (int k = 0; k < 8; k++) {
            float e = s1v + sv[k];
            e = (e > 0.f) ? e : ALPHA_ * e;
            float pv = (am[k] > 0) ? __expf(e) : 0.f;
            p[k] = pv;
            rs_loc += pv;
        }
        __syncthreads();  // previous tile's P fully consumed
#pragma unroll
        for (int k = 0; k < 8; k++) P[jo + k][my_i] = p[k];
        __syncthreads();

        // ---- phase 2: acc[i] += P[i][j] * h[j][o] ----
        const unsigned short* hptr = hb + (size_t)jt * FD;
#pragma unroll 8
        for (int jl = 0; jl < TJ; jl++) {
            float hv = bf2f(hptr[(size_t)jl * FD]);
            float4 p0 = *(const float4*)&P[jl][0];
            float4 p1 = *(const float4*)&P[jl][4];
            float4 p2 = *(const float4*)&P[jl][8];
            float4 p3 = *(const float4*)&P[jl][12];
            acc[0]  += p0.x * hv;  acc[1]  += p0.y * hv;
            acc[2]  += p0.z * hv;  acc[3]  += p0.w * hv;
            acc[4]  += p1.x * hv;  acc[5]  += p1.y * hv;
            acc[6]  += p1.z * hv;  acc[7]  += p1.w * hv;
            acc[8]  += p2.x * hv;  acc[9]  += p2.y * hv;
            acc[10] += p2.z * hv;  acc[11] += p2.w * hv;
            acc[12] += p3.x * hv;  acc[13] += p3.y * hv;
            acc[14] += p3.z * hv;  acc[15] += p3.w * hv;
        }
    }

    // ---- row-sum reduce (8 partials per row) ----
    __syncthreads();
    rs_part[t] = rs_loc;
    __syncthreads();
    if (t < TI) {
        float s = 0.f;
#pragma unroll
        for (int k = 0; k < 8; k++) s += rs_part[t * 8 + k];
        rs[t] = s;
    }
    __syncthreads();

    // ---- normalize + write (fp32 out) ----
#pragma unroll
    for (int i = 0; i < TI; i++) {
        float r = acc[i] / rs[i];
        out[((size_t)(b * N_ + i0 + i)) * FD + o] = r;
    }
}

// ---------------------------------------------------------------------------
extern "C" void kernel_launch(void* const* d_in, const int* in_sizes, int n_in,
                              void* d_out, int out_size, void* d_ws, size_t ws_size,
                              hipStream_t stream) {
    // Identify inputs by element count (robust to ordering):
    //   input = 8*2048*128 = 2097152, adj = 8*2048*2048 = 33554432,
    //   W = 128*128 = 16384, a = 256
    const void* xv = d_in[0];
    const void* adjv = d_in[1];
    const void* Wv = d_in[2];
    const void* av = d_in[3];
    for (int i = 0; i < n_in; i++) {
        switch (in_sizes[i]) {
            case 2097152:  xv = d_in[i]; break;
            case 33554432: adjv = d_in[i]; break;
            case 16384:    Wv = d_in[i]; break;
            case 256:      av = d_in[i]; break;
            default: break;
        }
    }
    const float* x   = (const float*)xv;
    const int* adj   = (const int*)adjv;
    const float* W   = (const float*)Wv;
    const float* a   = (const float*)av;
    float* out       = (float*)d_out;   // fp32 out, per reference

    // workspace layout: h_bf (4 MB) | s1 (64 KB) | s2 (64 KB)
    unsigned short* h_bf = (unsigned short*)d_ws;
    float* s1 = (float*)((char*)d_ws + (size_t)B_ * N_ * FD * sizeof(unsigned short));
    float* s2 = s1 + (size_t)B_ * N_;

    gat_h_kernel<<<B_ * N_, 128, 0, stream>>>(x, W, a, h_bf, s1, s2);
    gat_attn_kernel<<<dim3(N_ / TI, B_), 128, 0, stream>>>(adj, h_bf, s1, s2, out);
}

// Round 4
// 228.839 us; speedup vs baseline: 2.2017x; 2.2017x over previous
//
#include <hip/hip_runtime.h>
#include <stdint.h>

// GAT layer on MI355X: B=8, N=2048, F=128.
// h = x@W^T ; s1=h@a1 ; s2=h@a2 ; e=leaky(s1[i]+s2[j]); masked softmax; out=attn@h
// Scores rank-1 (no NxN score GEMM). Floor: adj = 134 MB HBM read ~21 us.
//
// K0: W -> bf16 hi/lo split.
// K1: MFMA split-precision GEMM (xhi*Whi + xlo*Whi + xhi*Wlo), writes hT[b][o][j]
//     bf16 (transposed, B-frag-friendly) + s1/s2 via in-register reduce.
// K2: flash-style masked-softmax+PV with mfma_f32_16x16x32_bf16:
//     adj int4 prefetch (lane layout == A-frag layout), h tile in XOR-swizzled
//     LDS (conflict-free ds_read_b128), double-buffered, 1 barrier/chunk.
// Fallback if accuracy regresses: split P into bf16 hi+lo (2 MFMAs).

#define B_ 8
#define N_ 2048
#define FD 128
#define ALPHA_ 0.2f
#define TJ 128
#define NCHUNK (N_ / TJ)

typedef __attribute__((ext_vector_type(8))) short short8;
typedef __attribute__((ext_vector_type(4))) float f32x4;

// 16B-chunk index of h-tile element block (o, jc) with XOR swizzle (jc in 16B units)
#define HCHUNK(o, jc) ((((o) * 16) + ((jc) ^ ((o) & 15))) * 8)  // offset in ushorts

__device__ __forceinline__ float bf2f(unsigned short u) {
    union { uint32_t i; float f; } v; v.i = ((uint32_t)u) << 16; return v.f;
}
__device__ __forceinline__ unsigned short f2bf(float f) {
    union { float f; uint32_t i; } v; v.f = f;
    uint32_t x = v.i;
    uint32_t r = (x + 0x7fffu + ((x >> 16) & 1u)) >> 16;  // RNE
    return (unsigned short)r;
}

// ---------------------------------------------------------------------------
// Kernel 0: W fp32 -> bf16 hi/lo
// ---------------------------------------------------------------------------
__global__ __launch_bounds__(256) void gat_wcvt(
    const float* __restrict__ W,
    unsigned short* __restrict__ Whi, unsigned short* __restrict__ Wlo)
{
    int i = blockIdx.x * 256 + threadIdx.x;  // grid 64 -> 16384
    float v = W[i];
    unsigned short hi = f2bf(v);
    Whi[i] = hi;
    Wlo[i] = f2bf(v - bf2f(hi));
}

// ---------------------------------------------------------------------------
// Kernel 1: h = x@W^T via split-bf16 MFMA; writes hT (b,o,j) bf16 + s1/s2.
// 256 blocks x 256 threads; block = 64 rows x 128 outs; wave w: rows w*16..+16.
// A-frag: A[m=lane&15][k=quad*8+jj] = x[row][f];  B-frag: B[k][n=lane&15]=W[o][f].
// C/D: col=lane&15, row=quad*4+reg  (m89/m91-verified layout).
// ---------------------------------------------------------------------------
__global__ __launch_bounds__(256) void gat_h(
    const float* __restrict__ x,
    const unsigned short* __restrict__ Whi,
    const unsigned short* __restrict__ Wlo,
    const float* __restrict__ a,
    unsigned short* __restrict__ hT,
    float* __restrict__ s1o, float* __restrict__ s2o)
{
    const int bid = blockIdx.x;
    const int tid = threadIdx.x;
    const int w = tid >> 6;
    const int lane = tid & 63;
    const int m = lane & 15;
    const int quad = lane >> 4;
    const int arow = bid * 64 + w * 16 + m;   // A-operand row for this lane

    f32x4 acc[8];
#pragma unroll
    for (int ot = 0; ot < 8; ot++) acc[ot] = (f32x4){0.f, 0.f, 0.f, 0.f};

#pragma unroll
    for (int ks = 0; ks < 4; ks++) {
        const float* xp = x + (size_t)arow * FD + ks * 32 + quad * 8;
        float4 x0 = *(const float4*)xp;
        float4 x1 = *(const float4*)(xp + 4);
        float xv[8] = {x0.x, x0.y, x0.z, x0.w, x1.x, x1.y, x1.z, x1.w};
        union { unsigned short us[8]; short8 v; } ahi, alo;
#pragma unroll
        for (int jj = 0; jj < 8; jj++) {
            unsigned short hi = f2bf(xv[jj]);
            ahi.us[jj] = hi;
            alo.us[jj] = f2bf(xv[jj] - bf2f(hi));
        }
#pragma unroll
        for (int ot = 0; ot < 8; ot++) {
            const size_t woff = (size_t)(ot * 16 + m) * FD + ks * 32 + quad * 8;
            union { uint4 u; short8 v; } bh, bl;
            bh.u = *(const uint4*)(Whi + woff);
            bl.u = *(const uint4*)(Wlo + woff);
            acc[ot] = __builtin_amdgcn_mfma_f32_16x16x32_bf16(ahi.v, bh.v, acc[ot], 0, 0, 0);
            acc[ot] = __builtin_amdgcn_mfma_f32_16x16x32_bf16(alo.v, bh.v, acc[ot], 0, 0, 0);
            acc[ot] = __builtin_amdgcn_mfma_f32_16x16x32_bf16(ahi.v, bl.v, acc[ot], 0, 0, 0);
        }
    }

    // Epilogue: store hT (transposed, bf16) + s1/s2 partial reduce.
    const int rc0 = bid * 64 + w * 16 + quad * 4;  // C rows rc0..rc0+3
    const int bb = rc0 >> 11;                      // batch (64-row blocks never straddle)
    const int jb = rc0 & (N_ - 1);
    unsigned short* hTb = hT + (size_t)bb * FD * N_;
    float s1p[4] = {0.f, 0.f, 0.f, 0.f};
    float s2p[4] = {0.f, 0.f, 0.f, 0.f};
#pragma unroll
    for (int ot = 0; ot < 8; ot++) {
        const int o = ot * 16 + m;
        uint32_t p0 = (uint32_t)f2bf(acc[ot][0]) | ((uint32_t)f2bf(acc[ot][1]) << 16);
        uint32_t p1 = (uint32_t)f2bf(acc[ot][2]) | ((uint32_t)f2bf(acc[ot][3]) << 16);
        *(uint32_t*)(hTb + (size_t)o * N_ + jb)     = p0;
        *(uint32_t*)(hTb + (size_t)o * N_ + jb + 2) = p1;
        float a1v = a[o], a2v = a[FD + o];
#pragma unroll
        for (int r = 0; r < 4; r++) {
            s1p[r] += acc[ot][r] * a1v;
            s2p[r] += acc[ot][r] * a2v;
        }
    }
#pragma unroll
    for (int off = 8; off >= 1; off >>= 1) {
#pragma unroll
        for (int r = 0; r < 4; r++) {
            s1p[r] += __shfl_xor(s1p[r], off);
            s2p[r] += __shfl_xor(s2p[r], off);
        }
    }
    if (m == 0) {
#pragma unroll
        for (int r = 0; r < 4; r++) {
            s1o[rc0 + r] = s1p[r];
            s2o[rc0 + r] = s2p[r];
        }
    }
}

// ---------------------------------------------------------------------------
// Kernel 2: fused masked-softmax + PV (MFMA).
// 512 blocks (b = bid>>6, i0 = (bid&63)*32) x 256 threads (4 waves).
// Wave w: i-rows [i0 + (w>>1)*16, +16), o-tiles [(w&1)*4, +4).
// Per 128-j chunk: adj/h/s2 prefetched (regs / swizzled LDS double-buffer),
// P computed in A-frag layout, 16 MFMAs/wave, 1 barrier.
// ---------------------------------------------------------------------------
__global__ __launch_bounds__(256) void gat_attn(
    const int* __restrict__ adj,
    const unsigned short* __restrict__ hT,
    const float* __restrict__ s1,
    const float* __restrict__ s2,
    float* __restrict__ out)
{
    __shared__ __align__(16) unsigned short hbuf[2][FD * TJ];  // 2 x 32 KB
    __shared__ __align__(16) float s2buf[2][TJ];               // 2 x 512 B

    const int bid = blockIdx.x;
    const int b = bid >> 6;
    const int i0 = (bid & 63) * 32;
    const int tid = threadIdx.x;
    const int lane = tid & 63;
    const int w = tid >> 6;
    const int m = lane & 15;
    const int quad = lane >> 4;
    const int ihalf = w >> 1;
    const int ohalf = w & 1;

    const int irow = i0 + ihalf * 16 + m;  // this lane's P row (A-frag m)
    const float s1v = s1[b * N_ + irow];
    const int* adjrow = adj + ((size_t)(b * N_ + irow)) * N_;
    const unsigned short* hTb = hT + (size_t)b * FD * N_;
    const float* s2b = s2 + b * N_;

    // ---- prologue: chunk 0 ----
    int4 acur[8];
#pragma unroll
    for (int ks = 0; ks < 4; ks++) {
        acur[2 * ks]     = *(const int4*)(adjrow + ks * 32 + quad * 8);
        acur[2 * ks + 1] = *(const int4*)(adjrow + ks * 32 + quad * 8 + 4);
    }
    {
        uint4 g[8];
#pragma unroll
        for (int it = 0; it < 8; it++) {
            int cid = it * 256 + tid;
            int o = cid >> 4, jc = cid & 15;
            g[it] = *(const uint4*)(hTb + (size_t)o * N_ + jc * 8);
        }
        float4 s2g;
        if (tid < 32) s2g = *(const float4*)(s2b + tid * 4);
#pragma unroll
        for (int it = 0; it < 8; it++) {
            int cid = it * 256 + tid;
            int o = cid >> 4, jc = cid & 15;
            *(uint4*)&hbuf[0][HCHUNK(o, jc)] = g[it];
        }
        if (tid < 32) *(float4*)&s2buf[0][tid * 4] = s2g;
    }
    __syncthreads();

    f32x4 acc[4];
#pragma unroll
    for (int t4 = 0; t4 < 4; t4++) acc[t4] = (f32x4){0.f, 0.f, 0.f, 0.f};
    float rs_loc = 0.f;

    for (int k = 0; k < NCHUNK; k++) {
        const int buf = k & 1;
        const bool more = (k + 1 < NCHUNK);
        int4 anext[8];
        uint4 gn[8];
        float4 s2n;
        if (more) {
            const int j1 = (k + 1) * TJ;
#pragma unroll
            for (int ks = 0; ks < 4; ks++) {
                anext[2 * ks]     = *(const int4*)(adjrow + j1 + ks * 32 + quad * 8);
                anext[2 * ks + 1] = *(const int4*)(adjrow + j1 + ks * 32 + quad * 8 + 4);
            }
#pragma unroll
            for (int it = 0; it < 8; it++) {
                int cid = it * 256 + tid;
                int o = cid >> 4, jc = cid & 15;
                gn[it] = *(const uint4*)(hTb + (size_t)o * N_ + j1 + jc * 8);
            }
            if (tid < 32) s2n = *(const float4*)(s2b + j1 + tid * 4);
        }

        // ---- compute chunk k ----
#pragma unroll
        for (int ks = 0; ks < 4; ks++) {
            float4 sa = *(const float4*)&s2buf[buf][ks * 32 + quad * 8];
            float4 sb = *(const float4*)&s2buf[buf][ks * 32 + quad * 8 + 4];
            float sarr[8] = {sa.x, sa.y, sa.z, sa.w, sb.x, sb.y, sb.z, sb.w};
            int4 A0 = acur[2 * ks], A1 = acur[2 * ks + 1];
            int aarr[8] = {A0.x, A0.y, A0.z, A0.w, A1.x, A1.y, A1.z, A1.w};
            union { unsigned short us[8]; short8 v; } af;
#pragma unroll
            for (int jj = 0; jj < 8; jj++) {
                float e = s1v + sarr[jj];
                e = (e > 0.f) ? e : (ALPHA_ * e);
                float p = (aarr[jj] > 0) ? __expf(e) : 0.f;
                rs_loc += p;
                af.us[jj] = f2bf(p);
            }
#pragma unroll
            for (int t4 = 0; t4 < 4; t4++) {
                const int o = (ohalf * 4 + t4) * 16 + m;  // B-frag n = lane&15 = m
                union { uint4 u; short8 v; } bf;
                bf.u = *(const uint4*)&hbuf[buf][HCHUNK(o, ks * 4 + quad)];
                acc[t4] = __builtin_amdgcn_mfma_f32_16x16x32_bf16(af.v, bf.v, acc[t4], 0, 0, 0);
            }
        }

        if (more) {
            // write prefetched chunk k+1 into buf^1 (safe: buf^1 reads ended
            // before the barrier that closed chunk k-1), then barrier.
#pragma unroll
            for (int it = 0; it < 8; it++) {
                int cid = it * 256 + tid;
                int o = cid >> 4, jc = cid & 15;
                *(uint4*)&hbuf[buf ^ 1][HCHUNK(o, jc)] = gn[it];
            }
            if (tid < 32) *(float4*)&s2buf[buf ^ 1][tid * 4] = s2n;
            __syncthreads();
#pragma unroll
            for (int q = 0; q < 8; q++) acur[q] = anext[q];
        }
    }

    // ---- row-sum finalize: lanes sharing m across quads hold partials ----
    rs_loc += __shfl_xor(rs_loc, 16);
    rs_loc += __shfl_xor(rs_loc, 32);
    float rinv[4];
#pragma unroll
    for (int r = 0; r < 4; r++) rinv[r] = 1.0f / __shfl(rs_loc, quad * 4 + r);

    // ---- write: C/D row = quad*4+r, col = ot*16+m ----
    float* outp = out + (size_t)(b * N_ + i0 + ihalf * 16) * FD;
#pragma unroll
    for (int t4 = 0; t4 < 4; t4++) {
        const int col = (ohalf * 4 + t4) * 16 + m;
#pragma unroll
        for (int r = 0; r < 4; r++) {
            outp[(size_t)(quad * 4 + r) * FD + col] = acc[t4][r] * rinv[r];
        }
    }
}

// ---------------------------------------------------------------------------
extern "C" void kernel_launch(void* const* d_in, const int* in_sizes, int n_in,
                              void* d_out, int out_size, void* d_ws, size_t ws_size,
                              hipStream_t stream) {
    const void* xv = d_in[0];
    const void* adjv = d_in[1];
    const void* Wv = d_in[2];
    const void* av = d_in[3];
    for (int i = 0; i < n_in; i++) {
        switch (in_sizes[i]) {
            case 2097152:  xv = d_in[i]; break;
            case 33554432: adjv = d_in[i]; break;
            case 16384:    Wv = d_in[i]; break;
            case 256:      av = d_in[i]; break;
            default: break;
        }
    }
    const float* x = (const float*)xv;
    const int* adj = (const int*)adjv;
    const float* W = (const float*)Wv;
    const float* a = (const float*)av;
    float* out = (float*)d_out;

    // ws: hT 4MB | Whi 32KB | Wlo 32KB | s1 64KB | s2 64KB  (4.19 MB total)
    char* p = (char*)d_ws;
    unsigned short* hT  = (unsigned short*)p;               p += (size_t)B_ * FD * N_ * 2;
    unsigned short* Whi = (unsigned short*)p;               p += (size_t)FD * FD * 2;
    unsigned short* Wlo = (unsigned short*)p;               p += (size_t)FD * FD * 2;
    float* s1 = (float*)p;                                  p += (size_t)B_ * N_ * 4;
    float* s2 = (float*)p;

    gat_wcvt<<<64, 256, 0, stream>>>(W, Whi, Wlo);
    gat_h<<<256, 256, 0, stream>>>(x, Whi, Wlo, a, hT, s1, s2);
    gat_attn<<<512, 256, 0, stream>>>(adj, hT, s1, s2, out);
}

// Round 5
// 225.330 us; speedup vs baseline: 2.2360x; 1.0156x over previous
//
#include <hip/hip_runtime.h>
#include <stdint.h>

// GAT layer on MI355X: B=8, N=2048, F=128.
// h = x@W^T ; s1=h@a1 ; s2=h@a2 ; e=leaky(s1[i]+s2[j]); masked softmax; out=attn@h
// Scores rank-1 (no NxN score GEMM). Floor: adj = 134 MB (L3-resident) read.
//
// K1 (gat_h): W fp32 -> bf16 swizzled LDS once per block; split-precision
//     x (bf16 hi+lo) x Whi MFMA; writes hT[b][o][j] bf16 + s1/s2 in-register.
// K2 (gat_attn): flash-style masked-softmax+PV, mfma_f32_16x16x32_bf16;
//     adj int4 register prefetch (lane layout == A-frag), h tile XOR-swizzled
//     LDS double-buffer, s2 preloaded once, 1 barrier per 128-j chunk.

#define B_ 8
#define N_ 2048
#define FD 128
#define ALPHA_ 0.2f
#define TJ 128
#define NCHUNK (N_ / TJ)

typedef __attribute__((ext_vector_type(8))) short short8;
typedef __attribute__((ext_vector_type(4))) float f32x4;

// 16B-chunk XOR swizzle for a 128x128-bf16 tile: row o, 16B-chunk jc.
// Bank check for b128 frag reads (lanes m=0..15, fixed jc): jc^m is a
// permutation of 0..15 -> each bank pair hit 2x -> 2-way = free (m136).
#define HCHUNK(o, jc) ((((o) * 16) + ((jc) ^ ((o) & 15))) * 8)  // ushort offset

__device__ __forceinline__ float bf2f(unsigned short u) {
    union { uint32_t i; float f; } v; v.i = ((uint32_t)u) << 16; return v.f;
}
__device__ __forceinline__ unsigned short f2bf(float f) {
    union { float f; uint32_t i; } v; v.f = f;
    uint32_t x = v.i;
    uint32_t r = (x + 0x7fffu + ((x >> 16) & 1u)) >> 16;  // RNE
    return (unsigned short)r;
}

// ---------------------------------------------------------------------------
// Kernel 1: h = x@W^T via split-bf16 MFMA; writes hT (b,o,j) bf16 + s1/s2.
// 256 blocks x 256 threads; block = 64 rows x 128 outs; wave w: rows w*16..+16.
// A-frag: A[m=lane&15][k=quad*8+jj] = x[row][f];  B-frag: B[k][n]=W[o=n][k].
// C/D: col=lane&15, row=quad*4+reg  (m89/m91-verified layout).
// ---------------------------------------------------------------------------
__global__ __launch_bounds__(256) void gat_h(
    const float* __restrict__ x,
    const float* __restrict__ W,
    const float* __restrict__ a,
    unsigned short* __restrict__ hT,
    float* __restrict__ s1o, float* __restrict__ s2o)
{
    __shared__ __align__(16) unsigned short Wlds[FD * FD];  // 32KB, swizzled

    const int bid = blockIdx.x;
    const int tid = threadIdx.x;
    const int w = tid >> 6;
    const int lane = tid & 63;
    const int m = lane & 15;
    const int quad = lane >> 4;
    const int arow = bid * 64 + w * 16 + m;   // A-operand row for this lane

    // ---- stage W (fp32 -> bf16) into swizzled LDS, once per block ----
#pragma unroll
    for (int it = 0; it < 8; it++) {
        int cid = it * 256 + tid;          // 2048 16B-chunks
        int o = cid >> 4, kc = cid & 15;
        const float* wp = W + (size_t)o * FD + kc * 8;
        float4 w0 = *(const float4*)wp;
        float4 w1 = *(const float4*)(wp + 4);
        uint4 pk;
        pk.x = (uint32_t)f2bf(w0.x) | ((uint32_t)f2bf(w0.y) << 16);
        pk.y = (uint32_t)f2bf(w0.z) | ((uint32_t)f2bf(w0.w) << 16);
        pk.z = (uint32_t)f2bf(w1.x) | ((uint32_t)f2bf(w1.y) << 16);
        pk.w = (uint32_t)f2bf(w1.z) | ((uint32_t)f2bf(w1.w) << 16);
        *(uint4*)&Wlds[HCHUNK(o, kc)] = pk;
    }
    __syncthreads();

    f32x4 acc[8];
#pragma unroll
    for (int ot = 0; ot < 8; ot++) acc[ot] = (f32x4){0.f, 0.f, 0.f, 0.f};

#pragma unroll
    for (int ks = 0; ks < 4; ks++) {
        const float* xp = x + (size_t)arow * FD + ks * 32 + quad * 8;
        float4 x0 = *(const float4*)xp;
        float4 x1 = *(const float4*)(xp + 4);
        float xv[8] = {x0.x, x0.y, x0.z, x0.w, x1.x, x1.y, x1.z, x1.w};
        union { unsigned short us[8]; short8 v; } ahi, alo;
#pragma unroll
        for (int jj = 0; jj < 8; jj++) {
            unsigned short hi = f2bf(xv[jj]);
            ahi.us[jj] = hi;
            alo.us[jj] = f2bf(xv[jj] - bf2f(hi));
        }
#pragma unroll
        for (int ot = 0; ot < 8; ot++) {
            union { uint4 u; short8 v; } bw;
            bw.u = *(const uint4*)&Wlds[HCHUNK(ot * 16 + m, ks * 4 + quad)];
            acc[ot] = __builtin_amdgcn_mfma_f32_16x16x32_bf16(ahi.v, bw.v, acc[ot], 0, 0, 0);
            acc[ot] = __builtin_amdgcn_mfma_f32_16x16x32_bf16(alo.v, bw.v, acc[ot], 0, 0, 0);
        }
    }

    // Epilogue: store hT (transposed, bf16) + s1/s2 partial reduce.
    const int rc0 = bid * 64 + w * 16 + quad * 4;  // C rows rc0..rc0+3
    const int bb = rc0 >> 11;                      // batch
    const int jb = rc0 & (N_ - 1);
    unsigned short* hTb = hT + (size_t)bb * FD * N_;
    float s1p[4] = {0.f, 0.f, 0.f, 0.f};
    float s2p[4] = {0.f, 0.f, 0.f, 0.f};
#pragma unroll
    for (int ot = 0; ot < 8; ot++) {
        const int o = ot * 16 + m;
        uint32_t p0 = (uint32_t)f2bf(acc[ot][0]) | ((uint32_t)f2bf(acc[ot][1]) << 16);
        uint32_t p1 = (uint32_t)f2bf(acc[ot][2]) | ((uint32_t)f2bf(acc[ot][3]) << 16);
        *(uint32_t*)(hTb + (size_t)o * N_ + jb)     = p0;
        *(uint32_t*)(hTb + (size_t)o * N_ + jb + 2) = p1;
        float a1v = a[o], a2v = a[FD + o];
#pragma unroll
        for (int r = 0; r < 4; r++) {
            s1p[r] += acc[ot][r] * a1v;
            s2p[r] += acc[ot][r] * a2v;
        }
    }
#pragma unroll
    for (int off = 8; off >= 1; off >>= 1) {
#pragma unroll
        for (int r = 0; r < 4; r++) {
            s1p[r] += __shfl_xor(s1p[r], off);
            s2p[r] += __shfl_xor(s2p[r], off);
        }
    }
    if (m == 0) {
#pragma unroll
        for (int r = 0; r < 4; r++) {
            s1o[rc0 + r] = s1p[r];
            s2o[rc0 + r] = s2p[r];
        }
    }
}

// ---------------------------------------------------------------------------
// Kernel 2: fused masked-softmax + PV (MFMA).
// 512 blocks (b = bid>>6, i0 = (bid&63)*32) x 256 threads (4 waves), 2 blk/CU.
// Wave w: i-rows [i0 + (w>>1)*16, +16), o-tiles [(w&1)*4, +4).
// Per 128-j chunk: adj prefetched in regs (lane layout == A-frag layout),
// h tile in swizzled LDS double-buffer, s2 preloaded once, 1 barrier/chunk.
// ---------------------------------------------------------------------------
__global__ __launch_bounds__(256) void gat_attn(
    const int* __restrict__ adj,
    const unsigned short* __restrict__ hT,
    const float* __restrict__ s1,
    const float* __restrict__ s2,
    float* __restrict__ out)
{
    __shared__ __align__(16) unsigned short hbuf[2][FD * TJ];  // 2 x 32 KB
    __shared__ __align__(16) float s2s[N_];                    // 8 KB

    const int bid = blockIdx.x;
    const int b = bid >> 6;
    const int i0 = (bid & 63) * 32;
    const int tid = threadIdx.x;
    const int lane = tid & 63;
    const int w = tid >> 6;
    const int m = lane & 15;
    const int quad = lane >> 4;
    const int ihalf = w >> 1;
    const int ohalf = w & 1;

    const int irow = i0 + ihalf * 16 + m;  // this lane's P row (A-frag m)
    const float s1v = s1[b * N_ + irow];
    const int* adjrow = adj + ((size_t)(b * N_ + irow)) * N_;
    const unsigned short* hTb = hT + (size_t)b * FD * N_;
    const float* s2b = s2 + b * N_;

    // ---- prologue: s2 preload + chunk 0 stage ----
#pragma unroll
    for (int it = 0; it < 2; it++) {
        int i4 = it * 256 + tid;
        *(float4*)&s2s[i4 * 4] = *(const float4*)(s2b + i4 * 4);
    }
    int4 acur[8];
#pragma unroll
    for (int ks = 0; ks < 4; ks++) {
        acur[2 * ks]     = *(const int4*)(adjrow + ks * 32 + quad * 8);
        acur[2 * ks + 1] = *(const int4*)(adjrow + ks * 32 + quad * 8 + 4);
    }
    {
        uint4 g[8];
#pragma unroll
        for (int it = 0; it < 8; it++) {
            int cid = it * 256 + tid;
            int o = cid >> 4, jc = cid & 15;
            g[it] = *(const uint4*)(hTb + (size_t)o * N_ + jc * 8);
        }
#pragma unroll
        for (int it = 0; it < 8; it++) {
            int cid = it * 256 + tid;
            int o = cid >> 4, jc = cid & 15;
            *(uint4*)&hbuf[0][HCHUNK(o, jc)] = g[it];
        }
    }
    __syncthreads();

    f32x4 acc[4];
#pragma unroll
    for (int t4 = 0; t4 < 4; t4++) acc[t4] = (f32x4){0.f, 0.f, 0.f, 0.f};
    float rs_loc = 0.f;

    for (int k = 0; k < NCHUNK; k++) {
        const int buf = k & 1;
        const bool more = (k + 1 < NCHUNK);
        int4 anext[8];
        uint4 gn[8];
        if (more) {
            const int j1 = (k + 1) * TJ;
#pragma unroll
            for (int ks = 0; ks < 4; ks++) {
                anext[2 * ks]     = *(const int4*)(adjrow + j1 + ks * 32 + quad * 8);
                anext[2 * ks + 1] = *(const int4*)(adjrow + j1 + ks * 32 + quad * 8 + 4);
            }
#pragma unroll
            for (int it = 0; it < 8; it++) {
                int cid = it * 256 + tid;
                int o = cid >> 4, jc = cid & 15;
                gn[it] = *(const uint4*)(hTb + (size_t)o * N_ + j1 + jc * 8);
            }
        }

        // ---- compute chunk k ----
#pragma unroll
        for (int ks = 0; ks < 4; ks++) {
            float4 sa = *(const float4*)&s2s[k * TJ + ks * 32 + quad * 8];
            float4 sb = *(const float4*)&s2s[k * TJ + ks * 32 + quad * 8 + 4];
            float sarr[8] = {sa.x, sa.y, sa.z, sa.w, sb.x, sb.y, sb.z, sb.w};
            int4 A0 = acur[2 * ks], A1 = acur[2 * ks + 1];
            int aarr[8] = {A0.x, A0.y, A0.z, A0.w, A1.x, A1.y, A1.z, A1.w};
            union { unsigned short us[8]; short8 v; } af;
#pragma unroll
            for (int jj = 0; jj < 8; jj++) {
                float e = s1v + sarr[jj];
                e = (e > 0.f) ? e : (ALPHA_ * e);
                float p = (aarr[jj] > 0) ? __expf(e) : 0.f;
                rs_loc += p;
                af.us[jj] = f2bf(p);
            }
#pragma unroll
            for (int t4 = 0; t4 < 4; t4++) {
                const int o = (ohalf * 4 + t4) * 16 + m;  // B-frag n = lane&15
                union { uint4 u; short8 v; } bf;
                bf.u = *(const uint4*)&hbuf[buf][HCHUNK(o, ks * 4 + quad)];
                acc[t4] = __builtin_amdgcn_mfma_f32_16x16x32_bf16(af.v, bf.v, acc[t4], 0, 0, 0);
            }
        }

        if (more) {
            // write prefetched chunk k+1 into buf^1 (its readers finished
            // before the barrier that closed chunk k-1), then barrier.
#pragma unroll
            for (int it = 0; it < 8; it++) {
                int cid = it * 256 + tid;
                int o = cid >> 4, jc = cid & 15;
                *(uint4*)&hbuf[buf ^ 1][HCHUNK(o, jc)] = gn[it];
            }
            __syncthreads();
#pragma unroll
            for (int q = 0; q < 8; q++) acur[q] = anext[q];
        }
    }

    // ---- row-sum finalize: partials live across quads for same m ----
    rs_loc += __shfl_xor(rs_loc, 16);
    rs_loc += __shfl_xor(rs_loc, 32);
    float rinv[4];
#pragma unroll
    for (int r = 0; r < 4; r++) rinv[r] = 1.0f / __shfl(rs_loc, quad * 4 + r);

    // ---- write: C/D row = quad*4+r, col = t-tile*16+m ----
    float* outp = out + (size_t)(b * N_ + i0 + ihalf * 16) * FD;
#pragma unroll
    for (int t4 = 0; t4 < 4; t4++) {
        const int col = (ohalf * 4 + t4) * 16 + m;
#pragma unroll
        for (int r = 0; r < 4; r++) {
            outp[(size_t)(quad * 4 + r) * FD + col] = acc[t4][r] * rinv[r];
        }
    }
}

// ---------------------------------------------------------------------------
extern "C" void kernel_launch(void* const* d_in, const int* in_sizes, int n_in,
                              void* d_out, int out_size, void* d_ws, size_t ws_size,
                              hipStream_t stream) {
    const void* xv = d_in[0];
    const void* adjv = d_in[1];
    const void* Wv = d_in[2];
    const void* av = d_in[3];
    for (int i = 0; i < n_in; i++) {
        switch (in_sizes[i]) {
            case 2097152:  xv = d_in[i]; break;
            case 33554432: adjv = d_in[i]; break;
            case 16384:    Wv = d_in[i]; break;
            case 256:      av = d_in[i]; break;
            default: break;
        }
    }
    const float* x = (const float*)xv;
    const int* adj = (const int*)adjv;
    const float* W = (const float*)Wv;
    const float* a = (const float*)av;
    float* out = (float*)d_out;

    // ws: hT 4MB | s1 64KB | s2 64KB
    char* p = (char*)d_ws;
    unsigned short* hT = (unsigned short*)p;  p += (size_t)B_ * FD * N_ * 2;
    float* s1 = (float*)p;                    p += (size_t)B_ * N_ * 4;
    float* s2 = (float*)p;

    gat_h<<<256, 256, 0, stream>>>(x, W, a, hT, s1, s2);
    gat_attn<<<512, 256, 0, stream>>>(adj, hT, s1, s2, out);
}